// Round 18
// baseline (76.092 us; speedup 1.0000x reference)
//
#include <hip/hip_runtime.h>
#include <hip/hip_bf16.h>

typedef __hip_bfloat16 bf16;
typedef short short8 __attribute__((ext_vector_type(8)));
typedef float f32x4 __attribute__((ext_vector_type(4)));
typedef int   int4v __attribute__((ext_vector_type(4)));

#define NB 8
#define NN 1024
#define NM 32
#define ND 128
#define NE 32
#define NODES (NB*NN)
#define NPB 4                       // nodes per edge-block
#define NR  (NPB*NM)                // 128 edge rows per block

// ws layout (bytes)
#define OFF_W1AT   0               // 128x128 bf16 (W1 rows 0-127, T)  [prep]
#define OFF_W1BT   32768           // 128x128 (W1 rows 128-255, T)    [prep]
#define OFF_W1CDT  65536           // 128x64                          [edges]
#define OFF_W2T    81920           // 128x128                         [compact]
#define OFF_WX1T   114688          // 128x128                         [compact]
#define OFF_WH1AT  147456          // 128x128 (Wh1 rows 0-127, T)     [node]
#define OFF_WH1BT  180224          // 128x128 (Wh1 rows 128-255, T)   [node compact]
#define OFF_WH2T   212992          // 128x128                         [node]
#define OFF_W2XT   245760          // 128x128 = (W2@Wx1)^T            [edges fast]
#define OFF_W2HT   278528          // 128x128 = (W2@Wh1b)^T           [node fast]
#define OFF_B2X    311296          // 128 f32 = b2@Wx1 + bx1
#define OFF_B2H    311808          // 128 f32 = b2@Wh1b
#define OFF_Y1     312320          // 8192x128 bf16 = emb@W1a + b1
#define OFF_Y2     (OFF_Y1 + 2097152)   // emb@W1b
#define NEED_FAST  ((size_t)OFF_Y2 + 2097152)

__device__ __forceinline__ float toF(bf16 x){ return __bfloat162float(x); }
__device__ __forceinline__ bf16  toB(float x){ return __float2bfloat16(x); }
__device__ __forceinline__ float rawF(short s){
  bf16 b; __builtin_memcpy(&b, &s, 2); return __bfloat162float(b);
}

// Barrier with LDS-only drain (skips vmcnt(0) store-ack stall).
__device__ __forceinline__ void bar_lds(){
  asm volatile("s_waitcnt lgkmcnt(0)" ::: "memory");
  __builtin_amdgcn_s_barrier();
}

// Defeat compiler rematerialization of hoisted weight loads.
__device__ __forceinline__ short8 pin8(short8 w){
  union { short8 s; int4v i; } u; u.s = w;
  asm volatile("" : "+v"(u.i));
  return u.s;
}

__device__ __forceinline__ void cp16f(bf16* d, const float* s){
  #pragma unroll
  for (int q = 0; q < 4; ++q){
    float4 a = ((const float4*)s)[q];
    d[q*4+0]=toB(a.x); d[q*4+1]=toB(a.y); d[q*4+2]=toB(a.z); d[q*4+3]=toB(a.w);
  }
}
__device__ __forceinline__ void cp8f(bf16* d, const float* s){
  #pragma unroll
  for (int q = 0; q < 2; ++q){
    float4 a = ((const float4*)s)[q];
    d[q*4+0]=toB(a.x); d[q*4+1]=toB(a.y); d[q*4+2]=toB(a.z); d[q*4+3]=toB(a.w);
  }
}
__device__ __forceinline__ void cp4f(bf16* d, const float* s){
  float4 a = *(const float4*)s;
  d[0]=toB(a.x); d[1]=toB(a.y); d[2]=toB(a.z); d[3]=toB(a.w);
}

#define MFMA(a,b,c) __builtin_amdgcn_mfma_f32_16x16x32_bf16((a),(b),(c),0,0,0)

// Merged: transposes (blocks 0-479) + compose GEMM (480-511) + biases (512).
__global__ __launch_bounds__(256) void k_trc(const float* __restrict__ w1,
    const float* __restrict__ w2, const float* __restrict__ wx1,
    const float* __restrict__ wh1, const float* __restrict__ wh2,
    const float* __restrict__ b2, const float* __restrict__ bx1,
    char* __restrict__ ws){
  const int blk = blockIdx.x;
  const int tid = threadIdx.x;
  if (blk < 480){   // transposes
    int i = blk*256 + tid;
    const float* src; int koff, KT, dst, e;
    if      (i <  16384){ src=w1;  koff=0;   KT=128; dst=OFF_W1AT;  e=i; }
    else if (i <  32768){ src=w1;  koff=128; KT=128; dst=OFF_W1BT;  e=i-16384; }
    else if (i <  40960){ src=w1;  koff=256; KT=64;  dst=OFF_W1CDT; e=i-32768; }
    else if (i <  57344){ src=w2;  koff=0;   KT=128; dst=OFF_W2T;   e=i-40960; }
    else if (i <  73728){ src=wx1; koff=0;   KT=128; dst=OFF_WX1T;  e=i-57344; }
    else if (i <  90112){ src=wh1; koff=0;   KT=128; dst=OFF_WH1AT; e=i-73728; }
    else if (i < 106496){ src=wh1; koff=128; KT=128; dst=OFF_WH1BT; e=i-90112; }
    else               { src=wh2; koff=0;   KT=128; dst=OFF_WH2T;  e=i-106496; }
    int c = e / KT, k = e - c*KT;
    ((bf16*)(ws+dst))[e] = toB(src[(size_t)(koff+k)*128 + c]);
    return;
  }
  if (blk == 512){  // biases
    const int k = tid;
    if (k < 128){
      float bx = 0.f, bh = 0.f;
      for (int q = 0; q < 128; ++q){
        const float b2q = b2[q];
        bx += b2q * wx1[q*128 + k];
        bh += b2q * wh1[(size_t)(128+q)*128 + k];
      }
      ((float*)(ws+OFF_B2X))[k] = bx + bx1[k];
      ((float*)(ws+OFF_B2H))[k] = bh;
    }
    return;
  }
  // compose: W2XT[c][k] = sum_q wx1[q][c]*w2[k][q]; same for wh1b -> W2HT
  const int bid2 = blk - 480;            // 0..31
  const int part = bid2 >> 4;            // 0=x, 1=h
  const int sub2 = bid2 & 15;
  const int r0   = (sub2 >> 1) * 16;     // c row tile
  const int ch   = sub2 & 1;             // col half
  const float* A = part ? (wh1 + 128*128) : wx1;   // rows q of [q][c]
  bf16* OUT = (bf16*)(ws + (part ? OFF_W2HT : OFF_W2XT));
  const int lane = tid & 63, wv = tid >> 6, lr = lane & 15, lk = lane >> 4;
  const int kcol = ch*64 + wv*16 + lr;
  f32x4 acc = {};
  #pragma unroll
  for (int kc = 0; kc < 4; ++kc){
    const int q0 = kc*32 + lk*8;
    short8 a, b;
    #pragma unroll
    for (int i = 0; i < 8; ++i){
      bf16 ta = toB(A[(size_t)(q0+i)*128 + r0 + lr]);
      bf16 tb = toB(w2[(size_t)kcol*128 + q0 + i]);
      short sa, sb; __builtin_memcpy(&sa,&ta,2); __builtin_memcpy(&sb,&tb,2);
      a[i] = sa; b[i] = sb;
    }
    acc = MFMA(a, b, acc);
  }
  #pragma unroll
  for (int r = 0; r < 4; ++r)
    OUT[(size_t)(r0 + lk*4 + r)*128 + kcol] = toB(acc[r]);
}

// Prep: Y1 = emb@W1a + b1, Y2 = emb@W1b (bf16 in ws)
__global__ __launch_bounds__(256) void k_prep(const float* __restrict__ emb,
    const float* __restrict__ eb1, char* __restrict__ ws){
  __shared__ __align__(16) bf16 sE[32][136];
  const int tid = threadIdx.x, g0 = blockIdx.x*32;
  { const int row = tid >> 3, sub = tid & 7;
    cp16f(&sE[row][sub*16], emb + (size_t)(g0+row)*ND + sub*16); }
  bar_lds();
  const int lane = tid & 63, wv = tid >> 6, lr = lane & 15, lk = lane >> 4;
  const int c0 = wv*16 + lr, c1 = (wv+4)*16 + lr;
  const short* wt[2] = {(const short*)(ws+OFF_W1AT), (const short*)(ws+OFF_W1BT)};
  bf16* yo[2] = {(bf16*)(ws+OFF_Y1), (bf16*)(ws+OFF_Y2)};
  #pragma unroll
  for (int t = 0; t < 2; ++t){
    f32x4 acc[2][2] = {};
    #pragma unroll
    for (int kc = 0; kc < 4; ++kc){
      const int k0 = kc*32 + lk*8;
      short8 a0 = *(const short8*)&sE[lr][k0];
      short8 a1 = *(const short8*)&sE[16+lr][k0];
      short8 w0 = *(const short8*)&wt[t][c0*128 + k0];
      short8 w1v= *(const short8*)&wt[t][c1*128 + k0];
      acc[0][0]=MFMA(a0,w0,acc[0][0]);  acc[1][0]=MFMA(a1,w0,acc[1][0]);
      acc[0][1]=MFMA(a0,w1v,acc[0][1]); acc[1][1]=MFMA(a1,w1v,acc[1][1]);
    }
    const float b0 = (t==0) ? eb1[c0] : 0.f;
    const float b1 = (t==0) ? eb1[c1] : 0.f;
    #pragma unroll
    for (int rt = 0; rt < 2; ++rt)
      #pragma unroll
      for (int r = 0; r < 4; ++r){
        const int orow = rt*16 + lk*4 + r;
        const size_t g = (size_t)(g0 + orow)*ND;
        yo[t][g + c0] = toB(acc[rt][0][r] + b0);
        yo[t][g + c1] = toB(acc[rt][1][r] + b1);
      }
  }
}

// FAST edge kernel v11: v8 (46.8us proven) + fused node-update tail.
// LDS = regA 34816 + sH 34816 + sUnit 1536 + sPx 512 + sE 4352 + sHb 4352
//     = 80384 B -> exactly 2 blocks/CU.
__global__ __launch_bounds__(512) void k_edges_fast(
    const float* __restrict__ emb,    const float* __restrict__ coords,
    const float* __restrict__ mask,   const float* __restrict__ edges,
    const float* __restrict__ xw2,    const float* __restrict__ xb2,
    const float* __restrict__ hb1,    const float* __restrict__ hb2,
    const int* __restrict__ nids,     const char* __restrict__ ws,
    float* __restrict__ out)
{
  const short* w1cdT = (const short*)(ws+OFF_W1CDT);
  const short* w2xT  = (const short*)(ws+OFF_W2XT);
  const bf16*  Y1    = (const bf16*)(ws+OFF_Y1);
  const bf16*  Y2    = (const bf16*)(ws+OFF_Y2);
  const float* B2X   = (const float*)(ws+OFF_B2X);
  const float* B2H   = (const float*)(ws+OFF_B2H);

  __shared__ __align__(16) char regA[NR*136*2];   // sDE (ph1) / sX (phX) / sP
  __shared__ __align__(16) bf16 sH[NR][136];      // Y12 -> H
  __shared__ __align__(16) bf16 sE[16][136];      // emb rows (4 valid)
  __shared__ __align__(16) bf16 sHb[16][136];     // Hbar rows (4 valid)
  __shared__ float sUnit[NR][3];
  __shared__ float sPx[NR];
  bf16 (*sDE)[72]  = (bf16(*)[72])regA;
  bf16 (*sX)[136]  = (bf16(*)[136])regA;
  bf16 (*sP)[136]  = (bf16(*)[136])regA;

  const int bid = blockIdx.x;
  const int nbk = ((bid & 7) << 8) + (bid >> 3);  // XCD-bijective (2048=8*256)
  const int g0  = nbk * NPB;
  const int bi  = g0 >> 10;
  const int tid = threadIdx.x;
  const int lane = tid & 63, wv = tid >> 6;
  const int lr = lane & 15, lk = lane >> 4;
  const int c0 = wv*16 + lr;

  // pinned weight fragments
  short8 rw1[2], rwx[4];
  #pragma unroll
  for (int kc = 0; kc < 2; ++kc)
    rw1[kc] = pin8(*(const short8*)&w1cdT[c0*64 + kc*32 + lk*8]);
  #pragma unroll
  for (int kc = 0; kc < 4; ++kc)
    rwx[kc] = pin8(*(const short8*)&w2xT[c0*128 + kc*32 + lk*8]);
  const float bxc  = B2X[c0];
  const float wxc  = xw2[c0];
  const float bx2v = xb2[0];
  float mv[NPB];
  #pragma unroll
  for (int n = 0; n < NPB; ++n) mv[n] = mask[g0+n];

  { // staging: 4 threads per edge-row; per-thread nids; emb rows -> sE
    const int row = tid >> 2, sub = tid & 3;
    const int node = row >> 5;
    const int j = nids[(size_t)(g0+node)*NM + (row & 31)];
    const float* cs = coords + (size_t)(g0+node)*3;
    const float* cj = coords + ((size_t)bi*NN + j)*3;
    const float rx = cs[0]-cj[0], ry = cs[1]-cj[1], rz = cs[2]-cj[2];
    const float d2 = rx*rx + ry*ry + rz*rz;
    const float dist = sqrtf(d2);
    if (sub == 0){
      const float inv = (d2 > 0.f) ? 1.f/dist : 0.f;  // nan_to_num
      sUnit[row][0]=rx*inv; sUnit[row][1]=ry*inv; sUnit[row][2]=rz*inv;
    }
    cp8f(&sDE[row][32 + sub*8],
         edges + ((size_t)(g0+node)*NM + (row&31))*NE + sub*8);
    #pragma unroll
    for (int q = 0; q < 8; ++q){
      const int dd = sub*8 + q, h = dd & 15;
      const float ang = dist * __expf(-0.6140226909f * (float)h); // ln(1e4)/15
      sDE[row][dd] = toB((dd < 16) ? __sinf(ang) : __cosf(ang));
    }
    // Y12 prefill (packed b128 stores)
    const bf16* y1p = Y1 + (size_t)(g0+node)*ND + sub*32;
    const bf16* y2p = Y2 + ((size_t)bi*NN + j)*ND + sub*32;
    #pragma unroll
    for (int h8 = 0; h8 < 4; ++h8){
      short8 a = *(const short8*)(y1p + h8*8);
      short8 b = *(const short8*)(y2p + h8*8);
      short8 o;
      #pragma unroll
      for (int q = 0; q < 8; ++q){
        bf16 rsum = toB(rawF(a[q]) + rawF(b[q]));
        short sr; __builtin_memcpy(&sr,&rsum,2);
        o[q] = sr;
      }
      *(short8*)&sH[row][sub*32 + h8*8] = o;
    }
    // emb rows for fused node update (1 elem/thread; rows 4..15 garbage OK)
    sE[tid >> 7][tid & 127] = toB(emb[(size_t)(g0 + (tid >> 7))*ND + (tid & 127)]);
  }
  bar_lds();   // B

  { // ph1: H = relu(Y12 + DE @ W1cd), K=64, RMW on sH; fused Hbar -> sHb
    float hsum[NPB] = {};
    #pragma unroll
    for (int t = 0; t < 8; ++t){
      f32x4 acc = {};
      #pragma unroll
      for (int kc = 0; kc < 2; ++kc){
        short8 a = *(const short8*)&sDE[t*16 + lr][kc*32 + lk*8];
        acc = MFMA(a, rw1[kc], acc);
      }
      #pragma unroll
      for (int r = 0; r < 4; ++r){
        const int orow = t*16 + lk*4 + r;
        const float hv = fmaxf(toF(sH[orow][c0]) + acc[r], 0.f);
        sH[orow][c0] = toB(hv);
        hsum[t>>1] += hv;
      }
    }
    #pragma unroll
    for (int n = 0; n < NPB; ++n){
      hsum[n] += __shfl_xor(hsum[n], 16);
      hsum[n] += __shfl_xor(hsum[n], 32);
    }
    if (lk == 0){   // Hbar (masked mean) kept in LDS for the fused node MLP
      #pragma unroll
      for (int n = 0; n < NPB; ++n)
        sHb[n][c0] = toB(hsum[n] * mv[n] * (1.f/32.f));
    }
  }
  bar_lds();   // C

  { // phX: sX = relu(H @ W2x + B2X) * wx2
    #pragma unroll
    for (int t = 0; t < 8; ++t){
      f32x4 acc = {};
      #pragma unroll
      for (int kc = 0; kc < 4; ++kc){
        short8 a = *(const short8*)&sH[t*16 + lr][kc*32 + lk*8];
        acc = MFMA(a, rwx[kc], acc);
      }
      #pragma unroll
      for (int r = 0; r < 4; ++r){
        const int orow = t*16 + lk*4 + r;
        sX[orow][c0] = toB(fmaxf(acc[r] + bxc, 0.f) * wxc);
      }
    }
  }
  bar_lds();   // E

  { // px[row] = sum_c sX[row][c] + bx2 (4 threads/row)
    const int row = tid >> 2, sub = tid & 3;
    float p = 0.f;
    #pragma unroll
    for (int c8 = 0; c8 < 4; ++c8){
      short8 x = *(const short8*)&sX[row][sub*32 + c8*8];
      #pragma unroll
      for (int q = 0; q < 8; ++q) p += rawF(x[q]);
    }
    p += __shfl_xor(p, 1); p += __shfl_xor(p, 2);
    if (sub == 0) sPx[row] = p + bx2v;
  }
  bar_lds();   // F  (regA/sX now dead -> reusable as sP)

  // coords epilogue + fused node layer 1 (independent data; same phase)
  if (tid < NR){
    const float px = sPx[tid];
    float v0 = sUnit[tid][0]*px, v1 = sUnit[tid][1]*px, v2 = sUnit[tid][2]*px;
    #pragma unroll
    for (int m = 1; m < 32; m <<= 1){
      v0 += __shfl_xor(v0, m);
      v1 += __shfl_xor(v1, m);
      v2 += __shfl_xor(v2, m);
    }
    const int node = tid >> 5, d = tid & 31;
    if (d < 3){
      const float s = (d==0) ? v0 : (d==1 ? v1 : v2);
      out[(size_t)NODES*ND + (size_t)(g0+node)*3 + d] =
          coords[(size_t)(g0+node)*3 + d] + s*(1.f/32.f);
    }
  }
  { // node layer 1: P = relu(emb@Wh1a + Hbar@W2h + bh1 + mask*B2H)
    const short* whaT = (const short*)(ws+OFF_WH1AT);
    const short* w2hT = (const short*)(ws+OFF_W2HT);
    f32x4 acc = {};
    #pragma unroll
    for (int kc = 0; kc < 4; ++kc){
      const int k0 = kc*32 + lk*8;
      short8 a = *(const short8*)&sE[lr][k0];
      short8 w = *(const short8*)&whaT[c0*128 + k0];
      acc = MFMA(a, w, acc);
    }
    #pragma unroll
    for (int kc = 0; kc < 4; ++kc){
      const int k0 = kc*32 + lk*8;
      short8 a = *(const short8*)&sHb[lr][k0];
      short8 w = *(const short8*)&w2hT[c0*128 + k0];
      acc = MFMA(a, w, acc);
    }
    if (lk == 0){
      const float b1c = hb1[c0], bhc = B2H[c0];
      #pragma unroll
      for (int r = 0; r < 4; ++r)
        sP[r][c0] = toB(fmaxf(acc[r] + b1c + mv[r]*bhc, 0.f));
    }
  }
  bar_lds();   // G

  { // node layer 2: out = P@Wh2 + bh2 + emb
    const short* wh2T = (const short*)(ws+OFF_WH2T);
    f32x4 acc = {};
    #pragma unroll
    for (int kc = 0; kc < 4; ++kc){
      const int k0 = kc*32 + lk*8;
      short8 a = *(const short8*)&sP[lr][k0];
      short8 w = *(const short8*)&wh2T[c0*128 + k0];
      acc = MFMA(a, w, acc);
    }
    if (lk == 0){
      const float b2c = hb2[c0];
      #pragma unroll
      for (int r = 0; r < 4; ++r){
        const size_t g = (size_t)(g0 + r)*ND;
        out[g + c0] = acc[r] + b2c + emb[g + c0];
      }
    }
  }
}

// COMPACT edge kernel (weights-only ws): round-2-proven K=320 layer 1.
__global__ __launch_bounds__(256) void k_edges_compact(
    const float* __restrict__ emb,   const float* __restrict__ coords,
    const float* __restrict__ mask,  const float* __restrict__ edges,
    const float* __restrict__ eb1,   const float* __restrict__ eb2,
    const float* __restrict__ xb1,   const float* __restrict__ xw2,
    const float* __restrict__ xb2,   const int* __restrict__ nids,
    const char* __restrict__ ws,     float* __restrict__ out)
{
  const short* w1aT  = (const short*)(ws+OFF_W1AT);
  const short* w1bT  = (const short*)(ws+OFF_W1BT);
  const short* w1cdT = (const short*)(ws+OFF_W1CDT);
  const short* w2T   = (const short*)(ws+OFF_W2T);
  const short* wx1T  = (const short*)(ws+OFF_WX1T);

  __shared__ __align__(16) bf16 sA[32][336];
  __shared__ __align__(16) bf16 sH[32][136];
  __shared__ __align__(16) bf16 sM[32][136];
  __shared__ float sUnit[32][3];
  __shared__ float sPx[32];
  __shared__ int   sIds[32];
  __shared__ float sSelfC[3];

  const int tid = threadIdx.x;
  const int nb  = blockIdx.x;
  const int bi  = nb >> 10;

  if (tid < 32) sIds[tid] = nids[nb*NM + tid];
  if (tid < 3)  sSelfC[tid] = coords[(size_t)nb*3 + tid];
  __syncthreads();

  {
    const int row = tid >> 3, sub = tid & 7;
    const int j = sIds[row];
    cp16f(&sA[row][sub*16],       emb + (size_t)nb*ND + sub*16);
    cp16f(&sA[row][128 + sub*16], emb + ((size_t)bi*NN + j)*ND + sub*16);
    cp4f (&sA[row][288 + sub*4],  edges + ((size_t)nb*NM + row)*NE + sub*4);
    float jx = coords[((size_t)bi*NN + j)*3 + 0];
    float jy = coords[((size_t)bi*NN + j)*3 + 1];
    float jz = coords[((size_t)bi*NN + j)*3 + 2];
    float rx = sSelfC[0]-jx, ry = sSelfC[1]-jy, rz = sSelfC[2]-jz;
    float d2 = rx*rx + ry*ry + rz*rz;
    float dist = sqrtf(d2);
    if (sub == 0){
      float inv = (d2 > 0.f) ? 1.f/dist : 0.f;
      sUnit[row][0]=rx*inv; sUnit[row][1]=ry*inv; sUnit[row][2]=rz*inv;
    }
    #pragma unroll
    for (int q = 0; q < 4; ++q){
      const int dd = sub*4 + q, h = dd & 15;
      float ang = dist * __expf(-0.6140226909f * (float)h);
      sA[row][256+dd] = toB((dd < 16) ? __sinf(ang) : __cosf(ang));
    }
  }
  __syncthreads();

  const int lane = tid & 63, wv = tid >> 6, lr = lane & 15, lk = lane >> 4;
  const int c0 = wv*16 + lr, c1 = (wv+4)*16 + lr;

  {
    f32x4 acc[2][2] = {};
    #pragma unroll
    for (int kc = 0; kc < 10; ++kc){
      const int k0 = kc*32 + lk*8;
      const short* wp; int kk, KT;
      if (kc < 4){ wp = w1aT; kk = k0; KT = 128; }
      else if (kc < 8){ wp = w1bT; kk = k0-128; KT = 128; }
      else { wp = w1cdT; kk = k0-256; KT = 64; }
      short8 a0 = *(const short8*)&sA[lr][k0];
      short8 a1 = *(const short8*)&sA[16+lr][k0];
      short8 w0 = *(const short8*)&wp[c0*KT + kk];
      short8 w1v= *(const short8*)&wp[c1*KT + kk];
      acc[0][0]=MFMA(a0,w0,acc[0][0]);  acc[1][0]=MFMA(a1,w0,acc[1][0]);
      acc[0][1]=MFMA(a0,w1v,acc[0][1]); acc[1][1]=MFMA(a1,w1v,acc[1][1]);
    }
    const float b0 = eb1[c0], b1 = eb1[c1];
    #pragma unroll
    for (int rt = 0; rt < 2; ++rt)
      #pragma unroll
      for (int r = 0; r < 4; ++r){
        const int orow = rt*16 + lk*4 + r;
        sH[orow][c0] = toB(fmaxf(acc[rt][0][r]+b0, 0.f));
        sH[orow][c1] = toB(fmaxf(acc[rt][1][r]+b1, 0.f));
      }
  }
  __syncthreads();

  {
    f32x4 acc[2][2] = {};
    #pragma unroll
    for (int kc = 0; kc < 4; ++kc){
      const int k0 = kc*32 + lk*8;
      short8 a0 = *(const short8*)&sH[lr][k0];
      short8 a1 = *(const short8*)&sH[16+lr][k0];
      short8 w0 = *(const short8*)&w2T[c0*128 + k0];
      short8 w1v= *(const short8*)&w2T[c1*128 + k0];
      acc[0][0]=MFMA(a0,w0,acc[0][0]);  acc[1][0]=MFMA(a1,w0,acc[1][0]);
      acc[0][1]=MFMA(a0,w1v,acc[0][1]); acc[1][1]=MFMA(a1,w1v,acc[1][1]);
    }
    const float b0 = eb2[c0], b1 = eb2[c1];
    #pragma unroll
    for (int rt = 0; rt < 2; ++rt)
      #pragma unroll
      for (int r = 0; r < 4; ++r){
        const int orow = rt*16 + lk*4 + r;
        sM[orow][c0] = toB(acc[rt][0][r] + b0);
        sM[orow][c1] = toB(acc[rt][1][r] + b1);
      }
  }
  __syncthreads();

  {
    f32x4 acc[2][2] = {};
    #pragma unroll
    for (int kc = 0; kc < 4; ++kc){
      const int k0 = kc*32 + lk*8;
      short8 a0 = *(const short8*)&sM[lr][k0];
      short8 a1 = *(const short8*)&sM[16+lr][k0];
      short8 w0 = *(const short8*)&wx1T[c0*128 + k0];
      short8 w1v= *(const short8*)&wx1T[c1*128 + k0];
      acc[0][0]=MFMA(a0,w0,acc[0][0]);  acc[1][0]=MFMA(a1,w0,acc[1][0]);
      acc[0][1]=MFMA(a0,w1v,acc[0][1]); acc[1][1]=MFMA(a1,w1v,acc[1][1]);
    }
    const float b0 = xb1[c0], b1 = xb1[c1];
    #pragma unroll
    for (int rt = 0; rt < 2; ++rt)
      #pragma unroll
      for (int r = 0; r < 4; ++r){
        const int orow = rt*16 + lk*4 + r;
        sH[orow][c0] = toB(fmaxf(acc[rt][0][r]+b0, 0.f));
        sH[orow][c1] = toB(fmaxf(acc[rt][1][r]+b1, 0.f));
      }
  }
  __syncthreads();

  {
    const int row = tid >> 3, sub = tid & 7;
    float p = 0.f;
    #pragma unroll
    for (int q = 0; q < 16; ++q){
      const int c = sub*16 + q;
      p += toF(sH[row][c]) * xw2[c];
    }
    p += __shfl_down(p,4,8); p += __shfl_down(p,2,8); p += __shfl_down(p,1,8);
    if (sub == 0) sPx[row] = p + xb2[0];
  }
  if (tid < 128){
    float s = 0.f;
    #pragma unroll
    for (int m = 0; m < 32; ++m) s += toF(sM[m][tid]);
    out[(size_t)nb*ND + tid] = s * mask[nb] * (1.f/32.f);
  }
  __syncthreads();
  if (tid < 3){
    float s = 0.f;
    #pragma unroll
    for (int m = 0; m < 32; ++m) s += sUnit[m][tid]*sPx[m];
    out[(size_t)NODES*ND + (size_t)nb*3 + tid] = sSelfC[tid] + s*(1.f/32.f);
  }
}

// Node phase (compact path only): out holds m_i; use WH1BT directly.
__global__ __launch_bounds__(256) void k_node(
    const float* __restrict__ emb, const float* __restrict__ mask,
    const float* __restrict__ hb1, const float* __restrict__ hb2,
    const char* __restrict__ ws, float* __restrict__ out)
{
  const short* whaT = (const short*)(ws+OFF_WH1AT);
  const short* whbT = (const short*)(ws+OFF_WH1BT);
  const short* wh2T = (const short*)(ws+OFF_WH2T);
  __shared__ __align__(16) bf16 sE[32][136];
  __shared__ __align__(16) bf16 sM[32][136];
  __shared__ __align__(16) bf16 sH[32][136];
  const int tid = threadIdx.x, g0 = blockIdx.x*32;
  const int lane = tid & 63, wv = tid >> 6, lr = lane & 15, lk = lane >> 4;
  const int c0 = wv*16 + lr, c1 = (wv+4)*16 + lr;

  short8 rwa[2][4], rwb[2][4], rw2[2][4];
  #pragma unroll
  for (int kc = 0; kc < 4; ++kc){
    rwa[0][kc] = *(const short8*)&whaT[c0*128 + kc*32 + lk*8];
    rwa[1][kc] = *(const short8*)&whaT[c1*128 + kc*32 + lk*8];
    rwb[0][kc] = *(const short8*)&whbT[c0*128 + kc*32 + lk*8];
    rwb[1][kc] = *(const short8*)&whbT[c1*128 + kc*32 + lk*8];
    rw2[0][kc] = *(const short8*)&wh2T[c0*128 + kc*32 + lk*8];
    rw2[1][kc] = *(const short8*)&wh2T[c1*128 + kc*32 + lk*8];
  }
  const float b1c0 = hb1[c0], b1c1 = hb1[c1];
  const float b2c0 = hb2[c0], b2c1 = hb2[c1];

  { const int row = tid >> 3, sub = tid & 7;
    cp16f(&sE[row][sub*16], emb + (size_t)(g0+row)*ND + sub*16);
    cp16f(&sM[row][sub*16], out + (size_t)(g0+row)*ND + sub*16); } // m_i
  bar_lds();
  {
    f32x4 acc[2][2] = {};
    #pragma unroll
    for (int kc = 0; kc < 4; ++kc){
      const int k0 = kc*32 + lk*8;
      short8 a0 = *(const short8*)&sE[lr][k0];
      short8 a1 = *(const short8*)&sE[16+lr][k0];
      acc[0][0]=MFMA(a0,rwa[0][kc],acc[0][0]); acc[1][0]=MFMA(a1,rwa[0][kc],acc[1][0]);
      acc[0][1]=MFMA(a0,rwa[1][kc],acc[0][1]); acc[1][1]=MFMA(a1,rwa[1][kc],acc[1][1]);
    }
    #pragma unroll
    for (int kc = 0; kc < 4; ++kc){
      const int k0 = kc*32 + lk*8;
      short8 a0 = *(const short8*)&sM[lr][k0];
      short8 a1 = *(const short8*)&sM[16+lr][k0];
      acc[0][0]=MFMA(a0,rwb[0][kc],acc[0][0]); acc[1][0]=MFMA(a1,rwb[0][kc],acc[1][0]);
      acc[0][1]=MFMA(a0,rwb[1][kc],acc[0][1]); acc[1][1]=MFMA(a1,rwb[1][kc],acc[1][1]);
    }
    #pragma unroll
    for (int rt = 0; rt < 2; ++rt)
      #pragma unroll
      for (int r = 0; r < 4; ++r){
        const int orow = rt*16 + lk*4 + r;
        sH[orow][c0] = toB(fmaxf(acc[rt][0][r] + b1c0, 0.f));
        sH[orow][c1] = toB(fmaxf(acc[rt][1][r] + b1c1, 0.f));
      }
  }
  bar_lds();
  {
    f32x4 acc[2][2] = {};
    #pragma unroll
    for (int kc = 0; kc < 4; ++kc){
      const int k0 = kc*32 + lk*8;
      short8 a0 = *(const short8*)&sH[lr][k0];
      short8 a1 = *(const short8*)&sH[16+lr][k0];
      acc[0][0]=MFMA(a0,rw2[0][kc],acc[0][0]); acc[1][0]=MFMA(a1,rw2[0][kc],acc[1][0]);
      acc[0][1]=MFMA(a0,rw2[1][kc],acc[0][1]); acc[1][1]=MFMA(a1,rw2[1][kc],acc[1][1]);
    }
    #pragma unroll
    for (int rt = 0; rt < 2; ++rt)
      #pragma unroll
      for (int r = 0; r < 4; ++r){
        const int orow = rt*16 + lk*4 + r;
        const size_t g = (size_t)(g0 + orow)*ND;
        out[g + c0] = acc[rt][0][r] + b2c0 + emb[g + c0];
        out[g + c1] = acc[rt][1][r] + b2c1 + emb[g + c1];
      }
  }
}

extern "C" void kernel_launch(void* const* d_in, const int* in_sizes, int n_in,
                              void* d_out, int out_size, void* d_ws, size_t ws_size,
                              hipStream_t stream) {
  const float* emb    = (const float*)d_in[0];
  const float* coords = (const float*)d_in[1];
  const float* mask   = (const float*)d_in[2];
  const float* edges  = (const float*)d_in[3];
  const float* we_w1  = (const float*)d_in[4];
  const float* we_b1  = (const float*)d_in[5];
  const float* we_w2  = (const float*)d_in[6];
  const float* we_b2  = (const float*)d_in[7];
  const float* wx_w1  = (const float*)d_in[8];
  const float* wx_b1  = (const float*)d_in[9];
  const float* wx_w2  = (const float*)d_in[10];
  const float* wx_b2  = (const float*)d_in[11];
  const float* wh_w1  = (const float*)d_in[12];
  const float* wh_b1  = (const float*)d_in[13];
  const float* wh_w2  = (const float*)d_in[14];
  const float* wh_b2  = (const float*)d_in[15];
  const int*   nids   = (const int*)d_in[16];
  float* out = (float*)d_out;
  char* ws = (char*)d_ws;
  const bool fast = (ws_size >= NEED_FAST);

  k_trc<<<(fast ? 513 : 480),256,0,stream>>>(we_w1, we_w2, wx_w1, wh_w1,
      wh_w2, we_b2, wx_b1, ws);

  if (fast){
    k_prep<<<NODES/32,256,0,stream>>>(emb, we_b1, ws);
    k_edges_fast<<<NODES/NPB,512,0,stream>>>(emb, coords, mask, edges,
        wx_w2, wx_b2, wh_b1, wh_b2, nids, ws, out);
  } else {
    k_edges_compact<<<NODES,256,0,stream>>>(emb, coords, mask, edges,
        we_b1, we_b2, wx_b1, wx_w2, wx_b2, nids, ws, out);
    k_node<<<NODES/32,256,0,stream>>>(emb, mask, wh_b1, wh_b2, ws, out);
  }
}

// Round 19
// 61.995 us; speedup vs baseline: 1.2274x; 1.2274x over previous
//
#include <hip/hip_runtime.h>
#include <hip/hip_bf16.h>

typedef __hip_bfloat16 bf16;
typedef short short8 __attribute__((ext_vector_type(8)));
typedef float f32x4 __attribute__((ext_vector_type(4)));
typedef int   int4v __attribute__((ext_vector_type(4)));

#define NB 8
#define NN 1024
#define NM 32
#define ND 128
#define NE 32
#define NODES (NB*NN)
#define NPB 4                       // nodes per edge-block
#define NR  (NPB*NM)                // 128 edge rows per block

// ws layout (bytes)
#define OFF_W1AT   0               // 128x128 bf16 (W1 rows 0-127, T)  [prep]
#define OFF_W1BT   32768           // 128x128 (W1 rows 128-255, T)    [prep]
#define OFF_W1CDT  65536           // 128x64                          [edges]
#define OFF_W2T    81920           // 128x128                         [compact]
#define OFF_WX1T   114688          // 128x128                         [compact]
#define OFF_WH1AT  147456          // 128x128 (Wh1 rows 0-127, T)     [node]
#define OFF_WH1BT  180224          // 128x128 (Wh1 rows 128-255, T)   [node compact]
#define OFF_WH2T   212992          // 128x128                         [node]
#define OFF_W2XT   245760          // 128x128 = (W2@Wx1)^T            [edges fast]
#define OFF_W2HT   278528          // 128x128 = (W2@Wh1b)^T           [node fast]
#define OFF_B2X    311296          // 128 f32 = b2@Wx1 + bx1
#define OFF_B2H    311808          // 128 f32 = b2@Wh1b
#define OFF_Y1     312320          // 8192x128 bf16 = emb@W1a + b1
#define OFF_Y2     (OFF_Y1 + 2097152)   // emb@W1b
#define NEED_FAST  ((size_t)OFF_Y2 + 2097152)

__device__ __forceinline__ float toF(bf16 x){ return __bfloat162float(x); }
__device__ __forceinline__ bf16  toB(float x){ return __float2bfloat16(x); }
__device__ __forceinline__ float rawF(short s){
  bf16 b; __builtin_memcpy(&b, &s, 2); return __bfloat162float(b);
}

// Barrier with LDS-only drain (skips vmcnt(0) store-ack stall).
__device__ __forceinline__ void bar_lds(){
  asm volatile("s_waitcnt lgkmcnt(0)" ::: "memory");
  __builtin_amdgcn_s_barrier();
}

// Defeat compiler rematerialization of hoisted weight loads.
__device__ __forceinline__ short8 pin8(short8 w){
  union { short8 s; int4v i; } u; u.s = w;
  asm volatile("" : "+v"(u.i));
  return u.s;
}

__device__ __forceinline__ void cp16f(bf16* d, const float* s){
  #pragma unroll
  for (int q = 0; q < 4; ++q){
    float4 a = ((const float4*)s)[q];
    d[q*4+0]=toB(a.x); d[q*4+1]=toB(a.y); d[q*4+2]=toB(a.z); d[q*4+3]=toB(a.w);
  }
}
__device__ __forceinline__ void cp8f(bf16* d, const float* s){
  #pragma unroll
  for (int q = 0; q < 2; ++q){
    float4 a = ((const float4*)s)[q];
    d[q*4+0]=toB(a.x); d[q*4+1]=toB(a.y); d[q*4+2]=toB(a.z); d[q*4+3]=toB(a.w);
  }
}
__device__ __forceinline__ void cp4f(bf16* d, const float* s){
  float4 a = *(const float4*)s;
  d[0]=toB(a.x); d[1]=toB(a.y); d[2]=toB(a.z); d[3]=toB(a.w);
}

#define MFMA(a,b,c) __builtin_amdgcn_mfma_f32_16x16x32_bf16((a),(b),(c),0,0,0)

// Merged: transposes (blocks 0-479) + compose GEMM (480-511) + biases (512).
__global__ __launch_bounds__(256) void k_trc(const float* __restrict__ w1,
    const float* __restrict__ w2, const float* __restrict__ wx1,
    const float* __restrict__ wh1, const float* __restrict__ wh2,
    const float* __restrict__ b2, const float* __restrict__ bx1,
    char* __restrict__ ws){
  const int blk = blockIdx.x;
  const int tid = threadIdx.x;
  if (blk < 480){   // transposes
    int i = blk*256 + tid;
    const float* src; int koff, KT, dst, e;
    if      (i <  16384){ src=w1;  koff=0;   KT=128; dst=OFF_W1AT;  e=i; }
    else if (i <  32768){ src=w1;  koff=128; KT=128; dst=OFF_W1BT;  e=i-16384; }
    else if (i <  40960){ src=w1;  koff=256; KT=64;  dst=OFF_W1CDT; e=i-32768; }
    else if (i <  57344){ src=w2;  koff=0;   KT=128; dst=OFF_W2T;   e=i-40960; }
    else if (i <  73728){ src=wx1; koff=0;   KT=128; dst=OFF_WX1T;  e=i-57344; }
    else if (i <  90112){ src=wh1; koff=0;   KT=128; dst=OFF_WH1AT; e=i-73728; }
    else if (i < 106496){ src=wh1; koff=128; KT=128; dst=OFF_WH1BT; e=i-90112; }
    else               { src=wh2; koff=0;   KT=128; dst=OFF_WH2T;  e=i-106496; }
    int c = e / KT, k = e - c*KT;
    ((bf16*)(ws+dst))[e] = toB(src[(size_t)(koff+k)*128 + c]);
    return;
  }
  if (blk == 512){  // biases
    const int k = tid;
    if (k < 128){
      float bx = 0.f, bh = 0.f;
      for (int q = 0; q < 128; ++q){
        const float b2q = b2[q];
        bx += b2q * wx1[q*128 + k];
        bh += b2q * wh1[(size_t)(128+q)*128 + k];
      }
      ((float*)(ws+OFF_B2X))[k] = bx + bx1[k];
      ((float*)(ws+OFF_B2H))[k] = bh;
    }
    return;
  }
  // compose: W2XT[c][k] = sum_q wx1[q][c]*w2[k][q]; same for wh1b -> W2HT
  const int bid2 = blk - 480;            // 0..31
  const int part = bid2 >> 4;            // 0=x, 1=h
  const int sub2 = bid2 & 15;
  const int r0   = (sub2 >> 1) * 16;     // c row tile
  const int ch   = sub2 & 1;             // col half
  const float* A = part ? (wh1 + 128*128) : wx1;   // rows q of [q][c]
  bf16* OUT = (bf16*)(ws + (part ? OFF_W2HT : OFF_W2XT));
  const int lane = tid & 63, wv = tid >> 6, lr = lane & 15, lk = lane >> 4;
  const int kcol = ch*64 + wv*16 + lr;
  f32x4 acc = {};
  #pragma unroll
  for (int kc = 0; kc < 4; ++kc){
    const int q0 = kc*32 + lk*8;
    short8 a, b;
    #pragma unroll
    for (int i = 0; i < 8; ++i){
      bf16 ta = toB(A[(size_t)(q0+i)*128 + r0 + lr]);
      bf16 tb = toB(w2[(size_t)kcol*128 + q0 + i]);
      short sa, sb; __builtin_memcpy(&sa,&ta,2); __builtin_memcpy(&sb,&tb,2);
      a[i] = sa; b[i] = sb;
    }
    acc = MFMA(a, b, acc);
  }
  #pragma unroll
  for (int r = 0; r < 4; ++r)
    OUT[(size_t)(r0 + lk*4 + r)*128 + kcol] = toB(acc[r]);
}

// Prep: Y1 = emb@W1a + b1, Y2 = emb@W1b (bf16 in ws)
__global__ __launch_bounds__(256) void k_prep(const float* __restrict__ emb,
    const float* __restrict__ eb1, char* __restrict__ ws){
  __shared__ __align__(16) bf16 sE[32][136];
  const int tid = threadIdx.x, g0 = blockIdx.x*32;
  { const int row = tid >> 3, sub = tid & 7;
    cp16f(&sE[row][sub*16], emb + (size_t)(g0+row)*ND + sub*16); }
  bar_lds();
  const int lane = tid & 63, wv = tid >> 6, lr = lane & 15, lk = lane >> 4;
  const int c0 = wv*16 + lr, c1 = (wv+4)*16 + lr;
  const short* wt[2] = {(const short*)(ws+OFF_W1AT), (const short*)(ws+OFF_W1BT)};
  bf16* yo[2] = {(bf16*)(ws+OFF_Y1), (bf16*)(ws+OFF_Y2)};
  #pragma unroll
  for (int t = 0; t < 2; ++t){
    f32x4 acc[2][2] = {};
    #pragma unroll
    for (int kc = 0; kc < 4; ++kc){
      const int k0 = kc*32 + lk*8;
      short8 a0 = *(const short8*)&sE[lr][k0];
      short8 a1 = *(const short8*)&sE[16+lr][k0];
      short8 w0 = *(const short8*)&wt[t][c0*128 + k0];
      short8 w1v= *(const short8*)&wt[t][c1*128 + k0];
      acc[0][0]=MFMA(a0,w0,acc[0][0]);  acc[1][0]=MFMA(a1,w0,acc[1][0]);
      acc[0][1]=MFMA(a0,w1v,acc[0][1]); acc[1][1]=MFMA(a1,w1v,acc[1][1]);
    }
    const float b0 = (t==0) ? eb1[c0] : 0.f;
    const float b1 = (t==0) ? eb1[c1] : 0.f;
    #pragma unroll
    for (int rt = 0; rt < 2; ++rt)
      #pragma unroll
      for (int r = 0; r < 4; ++r){
        const int orow = rt*16 + lk*4 + r;
        const size_t g = (size_t)(g0 + orow)*ND;
        yo[t][g + c0] = toB(acc[rt][0][r] + b0);
        yo[t][g + c1] = toB(acc[rt][1][r] + b1);
      }
  }
}

// FAST edge kernel v8 (round-13/15/17 proven, 46.8us): 2 GEMM phases.
__global__ __launch_bounds__(512) void k_edges_fast(
    const float* __restrict__ coords, const float* __restrict__ mask,
    const float* __restrict__ edges,  const float* __restrict__ xw2,
    const float* __restrict__ xb2,    const int* __restrict__ nids,
    const char* __restrict__ ws,      float* __restrict__ out)
{
  const short* w1cdT = (const short*)(ws+OFF_W1CDT);
  const short* w2xT  = (const short*)(ws+OFF_W2XT);
  const bf16*  Y1    = (const bf16*)(ws+OFF_Y1);
  const bf16*  Y2    = (const bf16*)(ws+OFF_Y2);
  const float* B2X   = (const float*)(ws+OFF_B2X);

  __shared__ __align__(16) char regA[NR*136*2];   // sDE (ph1) / sX (phX out)
  __shared__ __align__(16) bf16 sH[NR][136];      // Y12 -> H
  __shared__ float sUnit[NR][3];
  __shared__ float sPx[NR];
  bf16 (*sDE)[72]  = (bf16(*)[72])regA;
  bf16 (*sX)[136]  = (bf16(*)[136])regA;

  const int bid = blockIdx.x;
  const int nbk = ((bid & 7) << 8) + (bid >> 3);  // XCD-bijective (2048=8*256)
  const int g0  = nbk * NPB;
  const int bi  = g0 >> 10;
  const int tid = threadIdx.x;
  const int lane = tid & 63, wv = tid >> 6;
  const int lr = lane & 15, lk = lane >> 4;
  const int c0 = wv*16 + lr;

  // pinned weight fragments
  short8 rw1[2], rwx[4];
  #pragma unroll
  for (int kc = 0; kc < 2; ++kc)
    rw1[kc] = pin8(*(const short8*)&w1cdT[c0*64 + kc*32 + lk*8]);
  #pragma unroll
  for (int kc = 0; kc < 4; ++kc)
    rwx[kc] = pin8(*(const short8*)&w2xT[c0*128 + kc*32 + lk*8]);
  const float bxc  = B2X[c0];
  const float wxc  = xw2[c0];
  const float bx2v = xb2[0];
  float mv[NPB];
  #pragma unroll
  for (int n = 0; n < NPB; ++n) mv[n] = mask[g0+n];

  { // staging: 4 threads per edge-row; per-thread nids
    const int row = tid >> 2, sub = tid & 3;
    const int node = row >> 5;
    const int j = nids[(size_t)(g0+node)*NM + (row & 31)];
    const float* cs = coords + (size_t)(g0+node)*3;
    const float* cj = coords + ((size_t)bi*NN + j)*3;
    const float rx = cs[0]-cj[0], ry = cs[1]-cj[1], rz = cs[2]-cj[2];
    const float d2 = rx*rx + ry*ry + rz*rz;
    const float dist = sqrtf(d2);
    if (sub == 0){
      const float inv = (d2 > 0.f) ? 1.f/dist : 0.f;  // nan_to_num
      sUnit[row][0]=rx*inv; sUnit[row][1]=ry*inv; sUnit[row][2]=rz*inv;
    }
    cp8f(&sDE[row][32 + sub*8],
         edges + ((size_t)(g0+node)*NM + (row&31))*NE + sub*8);
    #pragma unroll
    for (int q = 0; q < 8; ++q){
      const int dd = sub*8 + q, h = dd & 15;
      const float ang = dist * __expf(-0.6140226909f * (float)h); // ln(1e4)/15
      sDE[row][dd] = toB((dd < 16) ? __sinf(ang) : __cosf(ang));
    }
    // Y12 prefill (packed b128 stores)
    const bf16* y1p = Y1 + (size_t)(g0+node)*ND + sub*32;
    const bf16* y2p = Y2 + ((size_t)bi*NN + j)*ND + sub*32;
    #pragma unroll
    for (int h8 = 0; h8 < 4; ++h8){
      short8 a = *(const short8*)(y1p + h8*8);
      short8 b = *(const short8*)(y2p + h8*8);
      short8 o;
      #pragma unroll
      for (int q = 0; q < 8; ++q){
        bf16 rsum = toB(rawF(a[q]) + rawF(b[q]));
        short sr; __builtin_memcpy(&sr,&rsum,2);
        o[q] = sr;
      }
      *(short8*)&sH[row][sub*32 + h8*8] = o;
    }
  }
  bar_lds();   // B

  { // ph1: H = relu(Y12 + DE @ W1cd), K=64, RMW on sH; fused Hbar
    float hsum[NPB] = {};
    #pragma unroll
    for (int t = 0; t < 8; ++t){
      f32x4 acc = {};
      #pragma unroll
      for (int kc = 0; kc < 2; ++kc){
        short8 a = *(const short8*)&sDE[t*16 + lr][kc*32 + lk*8];
        acc = MFMA(a, rw1[kc], acc);
      }
      #pragma unroll
      for (int r = 0; r < 4; ++r){
        const int orow = t*16 + lk*4 + r;
        const float hv = fmaxf(toF(sH[orow][c0]) + acc[r], 0.f);
        sH[orow][c0] = toB(hv);
        hsum[t>>1] += hv;
      }
    }
    #pragma unroll
    for (int n = 0; n < NPB; ++n){
      hsum[n] += __shfl_xor(hsum[n], 16);
      hsum[n] += __shfl_xor(hsum[n], 32);
    }
    if (lk == 0){   // Hbar (masked mean of H) staged into out emb region
      #pragma unroll
      for (int n = 0; n < NPB; ++n)
        out[(size_t)(g0+n)*ND + c0] = hsum[n] * mv[n] * (1.f/32.f);
    }
  }
  bar_lds();   // C

  { // phX: sX = relu(H @ W2x + B2X) * wx2
    #pragma unroll
    for (int t = 0; t < 8; ++t){
      f32x4 acc = {};
      #pragma unroll
      for (int kc = 0; kc < 4; ++kc){
        short8 a = *(const short8*)&sH[t*16 + lr][kc*32 + lk*8];
        acc = MFMA(a, rwx[kc], acc);
      }
      #pragma unroll
      for (int r = 0; r < 4; ++r){
        const int orow = t*16 + lk*4 + r;
        sX[orow][c0] = toB(fmaxf(acc[r] + bxc, 0.f) * wxc);
      }
    }
  }
  bar_lds();   // E

  { // px[row] = sum_c sX[row][c] + bx2 (4 threads/row)
    const int row = tid >> 2, sub = tid & 3;
    float p = 0.f;
    #pragma unroll
    for (int c8 = 0; c8 < 4; ++c8){
      short8 x = *(const short8*)&sX[row][sub*32 + c8*8];
      #pragma unroll
      for (int q = 0; q < 8; ++q) p += rawF(x[q]);
    }
    p += __shfl_xor(p, 1); p += __shfl_xor(p, 2);
    if (sub == 0) sPx[row] = p + bx2v;
  }
  bar_lds();   // F

  if (tid < NR){
    const float px = sPx[tid];
    float v0 = sUnit[tid][0]*px, v1 = sUnit[tid][1]*px, v2 = sUnit[tid][2]*px;
    #pragma unroll
    for (int m = 1; m < 32; m <<= 1){
      v0 += __shfl_xor(v0, m);
      v1 += __shfl_xor(v1, m);
      v2 += __shfl_xor(v2, m);
    }
    const int node = tid >> 5, d = tid & 31;
    if (d < 3){
      const float s = (d==0) ? v0 : (d==1 ? v1 : v2);
      out[(size_t)NODES*ND + (size_t)(g0+node)*3 + d] =
          coords[(size_t)(g0+node)*3 + d] + s*(1.f/32.f);
    }
  }
}

// COMPACT edge kernel (weights-only ws): round-2-proven K=320 layer 1.
__global__ __launch_bounds__(256) void k_edges_compact(
    const float* __restrict__ emb,   const float* __restrict__ coords,
    const float* __restrict__ mask,  const float* __restrict__ edges,
    const float* __restrict__ eb1,   const float* __restrict__ eb2,
    const float* __restrict__ xb1,   const float* __restrict__ xw2,
    const float* __restrict__ xb2,   const int* __restrict__ nids,
    const char* __restrict__ ws,     float* __restrict__ out)
{
  const short* w1aT  = (const short*)(ws+OFF_W1AT);
  const short* w1bT  = (const short*)(ws+OFF_W1BT);
  const short* w1cdT = (const short*)(ws+OFF_W1CDT);
  const short* w2T   = (const short*)(ws+OFF_W2T);
  const short* wx1T  = (const short*)(ws+OFF_WX1T);

  __shared__ __align__(16) bf16 sA[32][336];
  __shared__ __align__(16) bf16 sH[32][136];
  __shared__ __align__(16) bf16 sM[32][136];
  __shared__ float sUnit[32][3];
  __shared__ float sPx[32];
  __shared__ int   sIds[32];
  __shared__ float sSelfC[3];

  const int tid = threadIdx.x;
  const int nb  = blockIdx.x;
  const int bi  = nb >> 10;

  if (tid < 32) sIds[tid] = nids[nb*NM + tid];
  if (tid < 3)  sSelfC[tid] = coords[(size_t)nb*3 + tid];
  __syncthreads();

  {
    const int row = tid >> 3, sub = tid & 7;
    const int j = sIds[row];
    cp16f(&sA[row][sub*16],       emb + (size_t)nb*ND + sub*16);
    cp16f(&sA[row][128 + sub*16], emb + ((size_t)bi*NN + j)*ND + sub*16);
    cp4f (&sA[row][288 + sub*4],  edges + ((size_t)nb*NM + row)*NE + sub*4);
    float jx = coords[((size_t)bi*NN + j)*3 + 0];
    float jy = coords[((size_t)bi*NN + j)*3 + 1];
    float jz = coords[((size_t)bi*NN + j)*3 + 2];
    float rx = sSelfC[0]-jx, ry = sSelfC[1]-jy, rz = sSelfC[2]-jz;
    float d2 = rx*rx + ry*ry + rz*rz;
    float dist = sqrtf(d2);
    if (sub == 0){
      float inv = (d2 > 0.f) ? 1.f/dist : 0.f;
      sUnit[row][0]=rx*inv; sUnit[row][1]=ry*inv; sUnit[row][2]=rz*inv;
    }
    #pragma unroll
    for (int q = 0; q < 4; ++q){
      const int dd = sub*4 + q, h = dd & 15;
      float ang = dist * __expf(-0.6140226909f * (float)h);
      sA[row][256+dd] = toB((dd < 16) ? __sinf(ang) : __cosf(ang));
    }
  }
  __syncthreads();

  const int lane = tid & 63, wv = tid >> 6, lr = lane & 15, lk = lane >> 4;
  const int c0 = wv*16 + lr, c1 = (wv+4)*16 + lr;

  {
    f32x4 acc[2][2] = {};
    #pragma unroll
    for (int kc = 0; kc < 10; ++kc){
      const int k0 = kc*32 + lk*8;
      const short* wp; int kk, KT;
      if (kc < 4){ wp = w1aT; kk = k0; KT = 128; }
      else if (kc < 8){ wp = w1bT; kk = k0-128; KT = 128; }
      else { wp = w1cdT; kk = k0-256; KT = 64; }
      short8 a0 = *(const short8*)&sA[lr][k0];
      short8 a1 = *(const short8*)&sA[16+lr][k0];
      short8 w0 = *(const short8*)&wp[c0*KT + kk];
      short8 w1v= *(const short8*)&wp[c1*KT + kk];
      acc[0][0]=MFMA(a0,w0,acc[0][0]);  acc[1][0]=MFMA(a1,w0,acc[1][0]);
      acc[0][1]=MFMA(a0,w1v,acc[0][1]); acc[1][1]=MFMA(a1,w1v,acc[1][1]);
    }
    const float b0 = eb1[c0], b1 = eb1[c1];
    #pragma unroll
    for (int rt = 0; rt < 2; ++rt)
      #pragma unroll
      for (int r = 0; r < 4; ++r){
        const int orow = rt*16 + lk*4 + r;
        sH[orow][c0] = toB(fmaxf(acc[rt][0][r]+b0, 0.f));
        sH[orow][c1] = toB(fmaxf(acc[rt][1][r]+b1, 0.f));
      }
  }
  __syncthreads();

  {
    f32x4 acc[2][2] = {};
    #pragma unroll
    for (int kc = 0; kc < 4; ++kc){
      const int k0 = kc*32 + lk*8;
      short8 a0 = *(const short8*)&sH[lr][k0];
      short8 a1 = *(const short8*)&sH[16+lr][k0];
      short8 w0 = *(const short8*)&w2T[c0*128 + k0];
      short8 w1v= *(const short8*)&w2T[c1*128 + k0];
      acc[0][0]=MFMA(a0,w0,acc[0][0]);  acc[1][0]=MFMA(a1,w0,acc[1][0]);
      acc[0][1]=MFMA(a0,w1v,acc[0][1]); acc[1][1]=MFMA(a1,w1v,acc[1][1]);
    }
    const float b0 = eb2[c0], b1 = eb2[c1];
    #pragma unroll
    for (int rt = 0; rt < 2; ++rt)
      #pragma unroll
      for (int r = 0; r < 4; ++r){
        const int orow = rt*16 + lk*4 + r;
        sM[orow][c0] = toB(acc[rt][0][r] + b0);
        sM[orow][c1] = toB(acc[rt][1][r] + b1);
      }
  }
  __syncthreads();

  {
    f32x4 acc[2][2] = {};
    #pragma unroll
    for (int kc = 0; kc < 4; ++kc){
      const int k0 = kc*32 + lk*8;
      short8 a0 = *(const short8*)&sM[lr][k0];
      short8 a1 = *(const short8*)&sM[16+lr][k0];
      short8 w0 = *(const short8*)&wx1T[c0*128 + k0];
      short8 w1v= *(const short8*)&wx1T[c1*128 + k0];
      acc[0][0]=MFMA(a0,w0,acc[0][0]);  acc[1][0]=MFMA(a1,w0,acc[1][0]);
      acc[0][1]=MFMA(a0,w1v,acc[0][1]); acc[1][1]=MFMA(a1,w1v,acc[1][1]);
    }
    const float b0 = xb1[c0], b1 = xb1[c1];
    #pragma unroll
    for (int rt = 0; rt < 2; ++rt)
      #pragma unroll
      for (int r = 0; r < 4; ++r){
        const int orow = rt*16 + lk*4 + r;
        sH[orow][c0] = toB(fmaxf(acc[rt][0][r]+b0, 0.f));
        sH[orow][c1] = toB(fmaxf(acc[rt][1][r]+b1, 0.f));
      }
  }
  __syncthreads();

  {
    const int row = tid >> 3, sub = tid & 7;
    float p = 0.f;
    #pragma unroll
    for (int q = 0; q < 16; ++q){
      const int c = sub*16 + q;
      p += toF(sH[row][c]) * xw2[c];
    }
    p += __shfl_down(p,4,8); p += __shfl_down(p,2,8); p += __shfl_down(p,1,8);
    if (sub == 0) sPx[row] = p + xb2[0];
  }
  if (tid < 128){
    float s = 0.f;
    #pragma unroll
    for (int m = 0; m < 32; ++m) s += toF(sM[m][tid]);
    out[(size_t)nb*ND + tid] = s * mask[nb] * (1.f/32.f);
  }
  __syncthreads();
  if (tid < 3){
    float s = 0.f;
    #pragma unroll
    for (int m = 0; m < 32; ++m) s += sUnit[m][tid]*sPx[m];
    out[(size_t)NODES*ND + (size_t)nb*3 + tid] = sSelfC[tid] + s*(1.f/32.f);
  }
}

// Node phase. HB=1 (fast): out holds Hbar; use W2HT + mask*B2H bias.
//             HB=0 (compact): out holds m_i; use WH1BT directly.
template<int HB>
__global__ __launch_bounds__(256) void k_node(
    const float* __restrict__ emb, const float* __restrict__ mask,
    const float* __restrict__ hb1, const float* __restrict__ hb2,
    const char* __restrict__ ws, float* __restrict__ out)
{
  const short* whaT = (const short*)(ws+OFF_WH1AT);
  const short* whbT = (const short*)(ws + (HB ? OFF_W2HT : OFF_WH1BT));
  const short* wh2T = (const short*)(ws+OFF_WH2T);
  const float* b2h  = (const float*)(ws+OFF_B2H);
  __shared__ __align__(16) bf16 sE[32][136];
  __shared__ __align__(16) bf16 sM[32][136];
  __shared__ __align__(16) bf16 sH[32][136];
  __shared__ float sMask[32];
  const int tid = threadIdx.x, g0 = blockIdx.x*32;
  const int lane = tid & 63, wv = tid >> 6, lr = lane & 15, lk = lane >> 4;
  const int c0 = wv*16 + lr, c1 = (wv+4)*16 + lr;

  short8 rwa[2][4], rwb[2][4], rw2[2][4];
  #pragma unroll
  for (int kc = 0; kc < 4; ++kc){
    rwa[0][kc] = *(const short8*)&whaT[c0*128 + kc*32 + lk*8];
    rwa[1][kc] = *(const short8*)&whaT[c1*128 + kc*32 + lk*8];
    rwb[0][kc] = *(const short8*)&whbT[c0*128 + kc*32 + lk*8];
    rwb[1][kc] = *(const short8*)&whbT[c1*128 + kc*32 + lk*8];
    rw2[0][kc] = *(const short8*)&wh2T[c0*128 + kc*32 + lk*8];
    rw2[1][kc] = *(const short8*)&wh2T[c1*128 + kc*32 + lk*8];
  }
  const float b1c0 = hb1[c0], b1c1 = hb1[c1];
  const float b2c0 = hb2[c0], b2c1 = hb2[c1];
  const float bhc0 = HB ? b2h[c0] : 0.f;
  const float bhc1 = HB ? b2h[c1] : 0.f;

  { const int row = tid >> 3, sub = tid & 7;
    cp16f(&sE[row][sub*16], emb + (size_t)(g0+row)*ND + sub*16);
    cp16f(&sM[row][sub*16], out + (size_t)(g0+row)*ND + sub*16); } // Hbar/m_i
  if (tid < 32) sMask[tid] = mask[g0 + tid];
  bar_lds();
  {
    f32x4 acc[2][2] = {};
    #pragma unroll
    for (int kc = 0; kc < 4; ++kc){
      const int k0 = kc*32 + lk*8;
      short8 a0 = *(const short8*)&sE[lr][k0];
      short8 a1 = *(const short8*)&sE[16+lr][k0];
      acc[0][0]=MFMA(a0,rwa[0][kc],acc[0][0]); acc[1][0]=MFMA(a1,rwa[0][kc],acc[1][0]);
      acc[0][1]=MFMA(a0,rwa[1][kc],acc[0][1]); acc[1][1]=MFMA(a1,rwa[1][kc],acc[1][1]);
    }
    #pragma unroll
    for (int kc = 0; kc < 4; ++kc){
      const int k0 = kc*32 + lk*8;
      short8 a0 = *(const short8*)&sM[lr][k0];
      short8 a1 = *(const short8*)&sM[16+lr][k0];
      acc[0][0]=MFMA(a0,rwb[0][kc],acc[0][0]); acc[1][0]=MFMA(a1,rwb[0][kc],acc[1][0]);
      acc[0][1]=MFMA(a0,rwb[1][kc],acc[0][1]); acc[1][1]=MFMA(a1,rwb[1][kc],acc[1][1]);
    }
    #pragma unroll
    for (int rt = 0; rt < 2; ++rt)
      #pragma unroll
      for (int r = 0; r < 4; ++r){
        const int orow = rt*16 + lk*4 + r;
        const float mk = HB ? sMask[orow] : 0.f;
        sH[orow][c0] = toB(fmaxf(acc[rt][0][r] + b1c0 + mk*bhc0, 0.f));
        sH[orow][c1] = toB(fmaxf(acc[rt][1][r] + b1c1 + mk*bhc1, 0.f));
      }
  }
  bar_lds();
  {
    f32x4 acc[2][2] = {};
    #pragma unroll
    for (int kc = 0; kc < 4; ++kc){
      const int k0 = kc*32 + lk*8;
      short8 a0 = *(const short8*)&sH[lr][k0];
      short8 a1 = *(const short8*)&sH[16+lr][k0];
      acc[0][0]=MFMA(a0,rw2[0][kc],acc[0][0]); acc[1][0]=MFMA(a1,rw2[0][kc],acc[1][0]);
      acc[0][1]=MFMA(a0,rw2[1][kc],acc[0][1]); acc[1][1]=MFMA(a1,rw2[1][kc],acc[1][1]);
    }
    #pragma unroll
    for (int rt = 0; rt < 2; ++rt)
      #pragma unroll
      for (int r = 0; r < 4; ++r){
        const int orow = rt*16 + lk*4 + r;
        const size_t g = (size_t)(g0 + orow)*ND;
        out[g + c0] = acc[rt][0][r] + b2c0 + emb[g + c0];
        out[g + c1] = acc[rt][1][r] + b2c1 + emb[g + c1];
      }
  }
}

extern "C" void kernel_launch(void* const* d_in, const int* in_sizes, int n_in,
                              void* d_out, int out_size, void* d_ws, size_t ws_size,
                              hipStream_t stream) {
  const float* emb    = (const float*)d_in[0];
  const float* coords = (const float*)d_in[1];
  const float* mask   = (const float*)d_in[2];
  const float* edges  = (const float*)d_in[3];
  const float* we_w1  = (const float*)d_in[4];
  const float* we_b1  = (const float*)d_in[5];
  const float* we_w2  = (const float*)d_in[6];
  const float* we_b2  = (const float*)d_in[7];
  const float* wx_w1  = (const float*)d_in[8];
  const float* wx_b1  = (const float*)d_in[9];
  const float* wx_w2  = (const float*)d_in[10];
  const float* wx_b2  = (const float*)d_in[11];
  const float* wh_w1  = (const float*)d_in[12];
  const float* wh_b1  = (const float*)d_in[13];
  const float* wh_w2  = (const float*)d_in[14];
  const float* wh_b2  = (const float*)d_in[15];
  const int*   nids   = (const int*)d_in[16];
  float* out = (float*)d_out;
  char* ws = (char*)d_ws;
  const bool fast = (ws_size >= NEED_FAST);

  k_trc<<<(fast ? 513 : 480),256,0,stream>>>(we_w1, we_w2, wx_w1, wh_w1,
      wh_w2, we_b2, wx_b1, ws);

  if (fast){
    k_prep<<<NODES/32,256,0,stream>>>(emb, we_b1, ws);
    k_edges_fast<<<NODES/NPB,512,0,stream>>>(coords, mask, edges,
        wx_w2, wx_b2, nids, ws, out);
    k_node<1><<<NODES/32,256,0,stream>>>(emb, mask, wh_b1, wh_b2, ws, out);
  } else {
    k_edges_compact<<<NODES,256,0,stream>>>(emb, coords, mask, edges,
        we_b1, we_b2, wx_b1, wx_w2, wx_b2, nids, ws, out);
    k_node<0><<<NODES/32,256,0,stream>>>(emb, mask, wh_b1, wh_b2, ws, out);
  }
}